// Round 13
// baseline (367.874 us; speedup 1.0000x reference)
//
#include <hip/hip_runtime.h>
#include <hip/hip_bf16.h>

typedef unsigned short u16;
typedef unsigned int u32;
typedef __attribute__((ext_vector_type(8))) short short8;
typedef __attribute__((ext_vector_type(4))) float floatx4;

#define NB 32
#define NCI 256
#define NCO 256
#define NW 4096
#define NK 5

#define WSTEP 16384
#define W2_BYTES (40 * WSTEP)

#define XROWB 64
#define XROWS 260
#define XBUF (XROWS * XROWB)
#define XSWZ(r) ((((r) >> 1) & 3) << 4)

#define FENCE asm volatile("" ::: "memory")
#define LK0   asm volatile("s_waitcnt lgkmcnt(0)" ::: "memory")
#define VM0   asm volatile("s_waitcnt vmcnt(0)" ::: "memory")

__global__ void wprep(const float* __restrict__ wgt, u16* __restrict__ W2) {
    int i = blockIdx.x * 256 + threadIdx.x;
    if (i >= NCO * NCI * NK) return;
    int k  = i % NK;
    int ci = (i / NK) % NCI;
    int co = i / (NCI * NK);
    int cb = ci >> 5, cr = ci & 31;
    int s    = cb * NK + k;
    int slot = (cr >> 3) ^ ((co >> 1) & 3);
    __hip_bfloat16 h = __float2bfloat16(wgt[i]);
    W2[(size_t)(s * 256 + co) * 32 + slot * 8 + (cr & 7)] = *reinterpret_cast<u16*>(&h);
}

__device__ __forceinline__ u16 bf16bits(float f) {
    __hip_bfloat16 h = __float2bfloat16(f);
    return *reinterpret_cast<u16*>(&h);
}

__device__ __forceinline__ void gload_lds16(const void* gsrc, void* ldst) {
    __builtin_amdgcn_global_load_lds(
        (const __attribute__((address_space(1))) unsigned int*)gsrc,
        (__attribute__((address_space(3))) unsigned int*)ldst, 16, 0, 0);
}

// ---------------- REAL kernel: r9 structure verbatim (95.6 us, passed) ----------------

__global__ __launch_bounds__(512, 2)
void conv_mfma(const float* __restrict__ x, const u16* __restrict__ W2,
               const float* __restrict__ bias, float* __restrict__ out) {
    __shared__ __align__(16) char smem[2 * WSTEP + 2 * XBUF];
    char* const wlds = smem;
    char* const xlds = smem + 2 * WSTEP;

    const int bid  = blockIdx.x;
    const int wt   = bid & 15;
    const int b    = bid >> 4;
    const int tid  = threadIdx.x;
    const int lane = tid & 63;
    const int wave = tid >> 6;
    const int wm   = wave >> 2;
    const int wn   = wave & 3;
    const int mrow = lane & 15;
    const int g    = lane >> 4;
    const int w0   = wt * 256;

    floatx4 acc[8][4];
#pragma unroll
    for (int mi = 0; mi < 8; ++mi)
#pragma unroll
        for (int ni = 0; ni < 4; ++ni)
            acc[mi][ni] = (floatx4){0.f, 0.f, 0.f, 0.f};

    const float* xb   = x + (size_t)b * NCI * NW;
    const char*  wimg = (const char*)W2;

    const int wloc = tid & 255;
    const int h    = tid >> 8;
    const int soff0 = (2 + wloc) * XROWB + ((h * 32) ^ XSWZ(2 + wloc));
    const int soff1 = (2 + wloc) * XROWB + ((h * 32 + 16) ^ XSWZ(2 + wloc));
    const float* xcol = xb + w0 + wloc;

    const int hidx = wave * 16 + (lane & 15);
    const int hri  = hidx >> 5;
    const int hci  = hidx & 31;
    const int hwg  = (hri < 2) ? (w0 - 2 + hri) : (w0 + 256 + (hri - 2));
    const int hwc  = (hwg < 0) ? 0 : ((hwg > NW - 1) ? (NW - 1) : hwg);
    const bool hok = (hwg >= 0) && (hwg < NW);
    const int hrloc = (hri < 2) ? hri : (258 + (hri - 2));
    const int hoff  = hrloc * XROWB + (((hci >> 3) ^ ((hrloc >> 1) & 3)) * 16) + (hci & 7) * 2;

    {
        gload_lds16(wimg + (wave * 2) * 1024 + lane * 16, wlds + (wave * 2) * 1024);
        gload_lds16(wimg + (wave * 2 + 1) * 1024 + lane * 16, wlds + (wave * 2 + 1) * 1024);
        float v0[16];
#pragma unroll
        for (int j = 0; j < 16; ++j)
            v0[j] = xcol[(size_t)(h * 16 + j) * NW];
        float hvv0 = xb[(size_t)hci * NW + hwc];
        u32 p[8];
#pragma unroll
        for (int jp = 0; jp < 8; ++jp)
            p[jp] = (u32)bf16bits(v0[2 * jp]) | ((u32)bf16bits(v0[2 * jp + 1]) << 16);
        *(int4*)(xlds + soff0) = *(int4*)&p[0];
        *(int4*)(xlds + soff1) = *(int4*)&p[4];
        if ((lane & 63) < 16)
            *(u16*)(xlds + hoff) = bf16bits(hok ? hvv0 : 0.f);
        LK0; VM0;
    }
    FENCE; __builtin_amdgcn_s_barrier(); FENCE;

    float v[16];
    float hvv = 0.f;
    for (int cb = 0; cb < 8; ++cb) {
        const char* xcur = xlds + (cb & 1) * XBUF;
        char* xnxt       = xlds + ((cb + 1) & 1) * XBUF;
        const bool more  = (cb < 7);
#pragma unroll
        for (int t = 0; t < NK; ++t) {
            const int s = cb * NK + t;
            if (s < 39) {
                const char* src = wimg + (size_t)(s + 1) * WSTEP;
                char* dst = wlds + ((s + 1) & 1) * WSTEP;
                gload_lds16(src + (wave * 2) * 1024 + lane * 16, dst + (wave * 2) * 1024);
                gload_lds16(src + (wave * 2 + 1) * 1024 + lane * 16, dst + (wave * 2 + 1) * 1024);
            }
            FENCE;
            if (t < 4 && more) {
                const float* sx = xcol + (size_t)((cb + 1) * 32 + h * 16 + t * 4) * NW;
                v[t * 4 + 0] = sx[0];
                v[t * 4 + 1] = sx[(size_t)NW];
                v[t * 4 + 2] = sx[(size_t)2 * NW];
                v[t * 4 + 3] = sx[(size_t)3 * NW];
            }
            if (t == 0 && more)
                hvv = xb[(size_t)((cb + 1) * 32 + hci) * NW + hwc];
            FENCE;
            const char* wcur = wlds + (s & 1) * WSTEP;
            short8 af[8], bf[4];
#pragma unroll
            for (int mi = 0; mi < 8; ++mi) {
                int rw = wm * 128 + mi * 16 + mrow;
                af[mi] = *(const short8*)(wcur + rw * 64 + ((g * 16) ^ XSWZ(rw)));
            }
#pragma unroll
            for (int ni = 0; ni < 4; ++ni) {
                int rx = wn * 64 + ni * 16 + mrow + t;
                bf[ni] = *(const short8*)(xcur + rx * XROWB + ((g * 16) ^ XSWZ(rx)));
            }
            __builtin_amdgcn_s_setprio(1);
#pragma unroll
            for (int mi = 0; mi < 8; ++mi)
#pragma unroll
                for (int ni = 0; ni < 4; ++ni)
                    acc[mi][ni] = __builtin_amdgcn_mfma_f32_16x16x32_bf16(
                        af[mi], bf[ni], acc[mi][ni], 0, 0, 0);
            __builtin_amdgcn_s_setprio(0);
            if (t == 4 && more) {
                u32 p[8];
#pragma unroll
                for (int jp = 0; jp < 8; ++jp)
                    p[jp] = (u32)bf16bits(v[2 * jp]) | ((u32)bf16bits(v[2 * jp + 1]) << 16);
                *(int4*)(xnxt + soff0) = *(int4*)&p[0];
                *(int4*)(xnxt + soff1) = *(int4*)&p[4];
                if ((lane & 63) < 16)
                    *(u16*)(xnxt + hoff) = bf16bits(hok ? hvv : 0.f);
            }
            LK0; VM0;
            FENCE; __builtin_amdgcn_s_barrier(); FENCE;
        }
    }

#pragma unroll
    for (int mi = 0; mi < 8; ++mi) {
        int cobase = wm * 128 + mi * 16 + g * 4;
        float bv[4];
#pragma unroll
        for (int r = 0; r < 4; ++r) bv[r] = bias[cobase + r];
#pragma unroll
        for (int ni = 0; ni < 4; ++ni) {
            int col = w0 + wn * 64 + ni * 16 + mrow;
#pragma unroll
            for (int r = 0; r < 4; ++r)
                out[((size_t)b * NCO + cobase + r) * NW + col] =
                    acc[mi][ni][r] + bv[r];
        }
    }
}

// ---------------- ABLATION variants (scratch output; diagnosis only) ----------------
// MODE 1 = nodma, 2 = nofrag, 3 = skeleton (no dma/frag/x), 4 = nox

template<int MODE>
__global__ __launch_bounds__(512, 2)
void conv_abl(const float* __restrict__ x, const u16* __restrict__ W2,
              const float* __restrict__ bias, float* __restrict__ outs) {
    constexpr bool HAS_DMA  = (MODE != 1) && (MODE != 3);
    constexpr bool HAS_FRAG = (MODE != 2) && (MODE != 3);
    constexpr bool HAS_X    = (MODE != 4) && (MODE != 3);

    __shared__ __align__(16) char smem[2 * WSTEP + 2 * XBUF];
    char* const wlds = smem;
    char* const xlds = smem + 2 * WSTEP;

    const int bid  = blockIdx.x;
    const int wt   = bid & 15;
    const int b    = bid >> 4;
    const int tid  = threadIdx.x;
    const int lane = tid & 63;
    const int wave = tid >> 6;
    const int wm   = wave >> 2;
    const int wn   = wave & 3;
    const int mrow = lane & 15;
    const int g    = lane >> 4;
    const int w0   = wt * 256;

    floatx4 acc[8][4];
#pragma unroll
    for (int mi = 0; mi < 8; ++mi)
#pragma unroll
        for (int ni = 0; ni < 4; ++ni)
            acc[mi][ni] = (floatx4){0.f, 0.f, 0.f, 0.f};

    const float* xb   = x + (size_t)b * NCI * NW;
    const char*  wimg = (const char*)W2;

    const int wloc = tid & 255;
    const int h    = tid >> 8;
    const int soff0 = (2 + wloc) * XROWB + ((h * 32) ^ XSWZ(2 + wloc));
    const int soff1 = (2 + wloc) * XROWB + ((h * 32 + 16) ^ XSWZ(2 + wloc));
    const float* xcol = xb + w0 + wloc;

    const int hidx = wave * 16 + (lane & 15);
    const int hri  = hidx >> 5;
    const int hci  = hidx & 31;
    const int hwg  = (hri < 2) ? (w0 - 2 + hri) : (w0 + 256 + (hri - 2));
    const int hwc  = (hwg < 0) ? 0 : ((hwg > NW - 1) ? (NW - 1) : hwg);
    const bool hok = (hwg >= 0) && (hwg < NW);
    const int hrloc = (hri < 2) ? hri : (258 + (hri - 2));
    const int hoff  = hrloc * XROWB + (((hci >> 3) ^ ((hrloc >> 1) & 3)) * 16) + (hci & 7) * 2;

    // constant prologue (all modes): W(0) DMA + x(0) stage
    {
        gload_lds16(wimg + (wave * 2) * 1024 + lane * 16, wlds + (wave * 2) * 1024);
        gload_lds16(wimg + (wave * 2 + 1) * 1024 + lane * 16, wlds + (wave * 2 + 1) * 1024);
        float v0[16];
#pragma unroll
        for (int j = 0; j < 16; ++j)
            v0[j] = xcol[(size_t)(h * 16 + j) * NW];
        float hvv0 = xb[(size_t)hci * NW + hwc];
        u32 p[8];
#pragma unroll
        for (int jp = 0; jp < 8; ++jp)
            p[jp] = (u32)bf16bits(v0[2 * jp]) | ((u32)bf16bits(v0[2 * jp + 1]) << 16);
        *(int4*)(xlds + soff0) = *(int4*)&p[0];
        *(int4*)(xlds + soff1) = *(int4*)&p[4];
        if ((lane & 63) < 16)
            *(u16*)(xlds + hoff) = bf16bits(hok ? hvv0 : 0.f);
        LK0; VM0;
    }
    FENCE; __builtin_amdgcn_s_barrier(); FENCE;

    // preloaded constant frags for NOFRAG/SKELETON
    short8 pf_af[8], pf_bf[4];
    if constexpr (!HAS_FRAG) {
#pragma unroll
        for (int mi = 0; mi < 8; ++mi) {
            int rw = wm * 128 + mi * 16 + mrow;
            pf_af[mi] = *(const short8*)(wlds + rw * 64 + ((g * 16) ^ XSWZ(rw)));
        }
#pragma unroll
        for (int ni = 0; ni < 4; ++ni) {
            int rx = wn * 64 + ni * 16 + mrow;
            pf_bf[ni] = *(const short8*)(xlds + rx * XROWB + ((g * 16) ^ XSWZ(rx)));
        }
        LK0;
    }

    float v[16];
    float hvv = 0.f;
    for (int cb = 0; cb < 8; ++cb) {
        const char* xcur = xlds + (cb & 1) * XBUF;
        char* xnxt       = xlds + ((cb + 1) & 1) * XBUF;
        const bool more  = (cb < 7);
#pragma unroll
        for (int t = 0; t < NK; ++t) {
            const int s = cb * NK + t;
            if constexpr (HAS_DMA) {
                if (s < 39) {
                    const char* src = wimg + (size_t)(s + 1) * WSTEP;
                    char* dst = wlds + ((s + 1) & 1) * WSTEP;
                    gload_lds16(src + (wave * 2) * 1024 + lane * 16, dst + (wave * 2) * 1024);
                    gload_lds16(src + (wave * 2 + 1) * 1024 + lane * 16, dst + (wave * 2 + 1) * 1024);
                }
            }
            FENCE;
            if constexpr (HAS_X) {
                if (t < 4 && more) {
                    const float* sx = xcol + (size_t)((cb + 1) * 32 + h * 16 + t * 4) * NW;
                    v[t * 4 + 0] = sx[0];
                    v[t * 4 + 1] = sx[(size_t)NW];
                    v[t * 4 + 2] = sx[(size_t)2 * NW];
                    v[t * 4 + 3] = sx[(size_t)3 * NW];
                }
                if (t == 0 && more)
                    hvv = xb[(size_t)((cb + 1) * 32 + hci) * NW + hwc];
            }
            FENCE;
            short8 af[8], bf[4];
            if constexpr (HAS_FRAG) {
                const char* wcur = wlds + (s & 1) * WSTEP;
#pragma unroll
                for (int mi = 0; mi < 8; ++mi) {
                    int rw = wm * 128 + mi * 16 + mrow;
                    af[mi] = *(const short8*)(wcur + rw * 64 + ((g * 16) ^ XSWZ(rw)));
                }
#pragma unroll
                for (int ni = 0; ni < 4; ++ni) {
                    int rx = wn * 64 + ni * 16 + mrow + t;
                    bf[ni] = *(const short8*)(xcur + rx * XROWB + ((g * 16) ^ XSWZ(rx)));
                }
            } else {
#pragma unroll
                for (int mi = 0; mi < 8; ++mi) af[mi] = pf_af[mi];
#pragma unroll
                for (int ni = 0; ni < 4; ++ni) bf[ni] = pf_bf[ni];
            }
            __builtin_amdgcn_s_setprio(1);
#pragma unroll
            for (int mi = 0; mi < 8; ++mi)
#pragma unroll
                for (int ni = 0; ni < 4; ++ni)
                    acc[mi][ni] = __builtin_amdgcn_mfma_f32_16x16x32_bf16(
                        af[mi], bf[ni], acc[mi][ni], 0, 0, 0);
            __builtin_amdgcn_s_setprio(0);
            if constexpr (HAS_X) {
                if (t == 4 && more) {
                    u32 p[8];
#pragma unroll
                    for (int jp = 0; jp < 8; ++jp)
                        p[jp] = (u32)bf16bits(v[2 * jp]) | ((u32)bf16bits(v[2 * jp + 1]) << 16);
                    *(int4*)(xnxt + soff0) = *(int4*)&p[0];
                    *(int4*)(xnxt + soff1) = *(int4*)&p[4];
                    if ((lane & 63) < 16)
                        *(u16*)(xnxt + hoff) = bf16bits(hok ? hvv : 0.f);
                }
            }
            LK0; VM0;
            FENCE; __builtin_amdgcn_s_barrier(); FENCE;
        }
    }

    // scratch epilogue (aliased 16-block region; keeps acc + frag chain live)
#pragma unroll
    for (int mi = 0; mi < 8; ++mi) {
        int cobase = wm * 128 + mi * 16 + g * 4;
        float bv[4];
#pragma unroll
        for (int r = 0; r < 4; ++r) bv[r] = bias[cobase + r];
#pragma unroll
        for (int ni = 0; ni < 4; ++ni) {
            int col = w0 + wn * 64 + ni * 16 + mrow;
#pragma unroll
            for (int r = 0; r < 4; ++r)
                outs[((size_t)(bid & 15) * NCO + cobase + r) * 256 + (col & 255)] =
                    acc[mi][ni][r] + bv[r];
        }
    }
}

// ---------------- fallback ----------------

__global__ void conv_naive(const float* __restrict__ x, const float* __restrict__ wgt,
                           const float* __restrict__ bias, float* __restrict__ out) {
    int w  = blockIdx.x * 256 + threadIdx.x;
    int co = blockIdx.y;
    int b  = blockIdx.z;
    float acc = bias[co];
    for (int ci = 0; ci < NCI; ci++) {
        const float* xr = x + ((size_t)b * NCI + ci) * NW;
        const float* wr = wgt + ((size_t)co * NCI + ci) * NK;
#pragma unroll
        for (int k = 0; k < NK; k++) {
            int wi = w + k - 2;
            if (wi >= 0 && wi < NW) acc += xr[wi] * wr[k];
        }
    }
    out[((size_t)b * NCO + co) * NW + w] = acc;
}

// ---------------- launch ----------------

extern "C" void kernel_launch(void* const* d_in, const int* in_sizes, int n_in,
                              void* d_out, int out_size, void* d_ws, size_t ws_size,
                              hipStream_t stream) {
    const float* x    = (const float*)d_in[0];
    const float* wgt  = (const float*)d_in[1];
    const float* bias = (const float*)d_in[2];
    float* out        = (float*)d_out;

    if (ws_size < (size_t)(8 << 20)) {
        conv_naive<<<dim3(NW / 256, NCO, NB), 256, 0, stream>>>(x, wgt, bias, out);
        return;
    }

    u16* W2 = (u16*)d_ws;
    float* outs = (float*)((char*)d_ws + (1 << 20));

    wprep<<<(NCO * NCI * NK + 255) / 256, 256, 0, stream>>>(wgt, W2);
    conv_mfma<<<512, 512, 0, stream>>>(x, W2, bias, out);
    conv_abl<1><<<512, 512, 0, stream>>>(x, W2, bias, outs);  // nodma
    conv_abl<2><<<512, 512, 0, stream>>>(x, W2, bias, outs);  // nofrag
    conv_abl<3><<<512, 512, 0, stream>>>(x, W2, bias, outs);  // skeleton
    conv_abl<4><<<512, 512, 0, stream>>>(x, W2, bias, outs);  // nox
}

// Round 14
// 119.103 us; speedup vs baseline: 3.0887x; 3.0887x over previous
//
#include <hip/hip_runtime.h>
#include <hip/hip_bf16.h>

typedef unsigned short u16;
typedef unsigned int u32;
typedef __attribute__((ext_vector_type(8))) short short8;
typedef __attribute__((ext_vector_type(4))) float floatx4;

#define NB 32
#define NCI 256
#define NCO 256
#define NW 4096
#define NK 5

#define WSTEP 16384                     // per (cb,t): 256 co x 64 B rows (plain)
#define W2_BYTES (40 * WSTEP)           // 655360

#define XROWB 64                        // 32 ci' bf16
#define XROWS 132                       // rloc = (w-w0)+2, 0..131 (128w + halo)
#define XBUF (XROWS * XROWB)            // 8448 B
#define XSWZ(r) ((((r) >> 1) & 3) << 4) // conflict-free (r6-r12)

#define FENCE asm volatile("" ::: "memory")
#define LK0   asm volatile("s_waitcnt lgkmcnt(0)" ::: "memory")

// ---------------- pre-kernel: W fp32 -> bf16, [s=cb*5+k][co][32ci] 64-B rows ----------------

__global__ void wprep(const float* __restrict__ wgt, u16* __restrict__ W2) {
    int i = blockIdx.x * 256 + threadIdx.x;        // co*1280 + ci*5 + k
    if (i >= NCO * NCI * NK) return;
    int k  = i % NK;
    int ci = (i / NK) % NCI;
    int co = i / (NCI * NK);
    int cb = ci >> 5, cr = ci & 31;
    __hip_bfloat16 h = __float2bfloat16(wgt[i]);
    W2[((size_t)(cb * NK + k) * 256 + co) * 32 + cr] = *reinterpret_cast<u16*>(&h);
}

__device__ __forceinline__ u16 bf16bits(float f) {
    __hip_bfloat16 h = __float2bfloat16(f);
    return *reinterpret_cast<u16*>(&h);
}

// ---------------- fused conv: af from global (L1 port), bf from LDS (LDS port) ----------------
// grid 1024 = 32 w-tiles(128w) x 32 b; block 512 = 8 waves (4 co-strips x 2 w-strips),
// wave tile 64co x 64w, acc[4][4]=64. Per tap: issue next-tap af (4 global b128,
// L1/L2-hot, reg-dbuf) -> 4 bf ds_reads -> 16 MFMA. ONE raw barrier per cb.
// No DMA, no manual vmcnt: compiler waits cover af/x register consumption.

__global__ __launch_bounds__(512, 2)
void conv_mfma(const float* __restrict__ x, const u16* __restrict__ W2,
               const float* __restrict__ bias, float* __restrict__ out) {
    __shared__ __align__(16) char xlds[2 * XBUF];   // 16896 B

    const int bid  = blockIdx.x;
    const int wt   = bid & 31;
    const int b    = bid >> 5;
    const int tid  = threadIdx.x;
    const int lane = tid & 63;
    const int wave = tid >> 6;
    const int wm   = wave >> 1;        // co strip: wm*64 (0..3)
    const int wn   = wave & 1;         // w strip:  wn*64 (0..1)
    const int mrow = lane & 15;
    const int g    = lane >> 4;        // 0..3
    const int w0   = wt * 128;

    floatx4 acc[4][4];
#pragma unroll
    for (int mi = 0; mi < 4; ++mi)
#pragma unroll
        for (int ni = 0; ni < 4; ++ni)
            acc[mi][ni] = (floatx4){0.f, 0.f, 0.f, 0.f};

    const float* xb   = x + (size_t)b * NCI * NW;
    const char*  wimg = (const char*)W2;

    // x staging: thread -> one w (wloc), 8 ci (group cig); row rloc = 2 + wloc
    const int wloc = tid & 127;
    const int cig  = tid >> 7;         // 0..3
    const int soff = (2 + wloc) * XROWB + ((cig * 16) ^ XSWZ(2 + wloc));
    const float* xcol = xb + w0 + wloc;          // + ci*NW

    // halo: rows {0,1,130,131} = w {w0-2,w0-1,w0+128,w0+129}; lanes<16/wave write
    const int hidx = wave * 16 + (lane & 15);    // 0..127 -> (ri, ci)
    const int hri  = hidx >> 5;
    const int hci  = hidx & 31;
    const int hwg  = (hri < 2) ? (w0 - 2 + hri) : (w0 + 128 + (hri - 2));
    const int hwc  = (hwg < 0) ? 0 : ((hwg > NW - 1) ? (NW - 1) : hwg);
    const bool hok = (hwg >= 0) && (hwg < NW);
    const int hrloc = (hri < 2) ? hri : (130 + (hri - 2));
    const int hoff  = hrloc * XROWB + (((hci >> 3) ^ ((hrloc >> 1) & 3)) * 16) + (hci & 7) * 2;

    const int afrow = wm * 64 + mrow;  // +mi*16; af addr base row

#define AFLOAD(dst, s_)                                                         \
    {                                                                           \
        const char* wt_ = wimg + (size_t)(s_) * WSTEP;                          \
        _Pragma("unroll")                                                       \
        for (int mi = 0; mi < 4; ++mi)                                          \
            dst[mi] = *(const short8*)(wt_ + (afrow + mi * 16) * 64 + g * 16);  \
    }

    short8 af[2][4];
    float v[8];
    float hvv = 0.f;

    // ---------- prologue: stage x(0), issue x(1), load af(s=0) ----------
    {
        float v0[8];
#pragma unroll
        for (int j = 0; j < 8; ++j)
            v0[j] = xcol[(size_t)(cig * 8 + j) * NW];
        float hv0 = xb[(size_t)hci * NW + hwc];
        u32 p[4];
#pragma unroll
        for (int jp = 0; jp < 4; ++jp)
            p[jp] = (u32)bf16bits(v0[2 * jp]) | ((u32)bf16bits(v0[2 * jp + 1]) << 16);
        *(int4*)(xlds + soff) = *(int4*)p;
        if ((lane & 63) < 16)
            *(u16*)(xlds + hoff) = bf16bits(hok ? hv0 : 0.f);
        // issue x(1): private registers, consumed at cb0's pack
#pragma unroll
        for (int j = 0; j < 8; ++j)
            v[j] = xcol[(size_t)(32 + cig * 8 + j) * NW];
        hvv = xb[(size_t)(32 + hci) * NW + hwc];
        AFLOAD(af[0], 0);
        LK0;
    }
    FENCE; __builtin_amdgcn_s_barrier(); FENCE;

    // ---------- main loop: fully unrolled 8 cb x 5 taps ----------
#pragma unroll
    for (int cb = 0; cb < 8; ++cb) {
        const char* xcur = xlds + (cb & 1) * XBUF;
        char* xnxt       = xlds + ((cb + 1) & 1) * XBUF;
#pragma unroll
        for (int t = 0; t < NK; ++t) {
            const int s = cb * NK + t;          // compile-time
            if (s < 39)
                AFLOAD(af[(s + 1) & 1], s + 1);  // next tap's weights -> regs
            short8 bf[4];
#pragma unroll
            for (int ni = 0; ni < 4; ++ni) {
                int rx = wn * 64 + ni * 16 + mrow + t;
                bf[ni] = *(const short8*)(xcur + rx * XROWB + ((g * 16) ^ XSWZ(rx)));
            }
            __builtin_amdgcn_s_setprio(1);
#pragma unroll
            for (int mi = 0; mi < 4; ++mi)
#pragma unroll
                for (int ni = 0; ni < 4; ++ni)
                    acc[mi][ni] = __builtin_amdgcn_mfma_f32_16x16x32_bf16(
                        af[s & 1][mi], bf[ni], acc[mi][ni], 0, 0, 0);
            __builtin_amdgcn_s_setprio(0);
        }
        if (cb < 7) {
            // pack + write-late x(cb+1) into the other buffer
            u32 p[4];
#pragma unroll
            for (int jp = 0; jp < 4; ++jp)
                p[jp] = (u32)bf16bits(v[2 * jp]) | ((u32)bf16bits(v[2 * jp + 1]) << 16);
            *(int4*)(xnxt + soff) = *(int4*)p;
            if ((lane & 63) < 16)
                *(u16*)(xnxt + hoff) = bf16bits(hok ? hvv : 0.f);
            // issue x(cb+2): consumed at next cb's pack (≈5 taps of cover)
            if (cb < 6) {
                const float* sx = xcol + (size_t)((cb + 2) * 32 + cig * 8) * NW;
#pragma unroll
                for (int j = 0; j < 8; ++j)
                    v[j] = sx[(size_t)j * NW];
                hvv = xb[(size_t)((cb + 2) * 32 + hci) * NW + hwc];
            }
            LK0;                                 // ds_writes visible (vmem stays in flight)
            FENCE; __builtin_amdgcn_s_barrier(); FENCE;
        }
    }

    // ---------- epilogue: C/D col=lane&15 (w), row=g*4+r (co) ----------
#pragma unroll
    for (int mi = 0; mi < 4; ++mi) {
        int cobase = wm * 64 + mi * 16 + g * 4;
        float bv[4];
#pragma unroll
        for (int r = 0; r < 4; ++r) bv[r] = bias[cobase + r];
#pragma unroll
        for (int ni = 0; ni < 4; ++ni) {
            int col = w0 + wn * 64 + ni * 16 + mrow;
#pragma unroll
            for (int r = 0; r < 4; ++r)
                out[((size_t)b * NCO + cobase + r) * NW + col] =
                    acc[mi][ni][r] + bv[r];
        }
    }
#undef AFLOAD
}

// ---------------- fallback (ws too small): naive fp32 ----------------

__global__ void conv_naive(const float* __restrict__ x, const float* __restrict__ wgt,
                           const float* __restrict__ bias, float* __restrict__ out) {
    int w  = blockIdx.x * 256 + threadIdx.x;
    int co = blockIdx.y;
    int b  = blockIdx.z;
    float acc = bias[co];
    for (int ci = 0; ci < NCI; ci++) {
        const float* xr = x + ((size_t)b * NCI + ci) * NW;
        const float* wr = wgt + ((size_t)co * NCI + ci) * NK;
#pragma unroll
        for (int k = 0; k < NK; k++) {
            int wi = w + k - 2;
            if (wi >= 0 && wi < NW) acc += xr[wi] * wr[k];
        }
    }
    out[((size_t)b * NCO + co) * NW + w] = acc;
}

// ---------------- launch ----------------

extern "C" void kernel_launch(void* const* d_in, const int* in_sizes, int n_in,
                              void* d_out, int out_size, void* d_ws, size_t ws_size,
                              hipStream_t stream) {
    const float* x    = (const float*)d_in[0];
    const float* wgt  = (const float*)d_in[1];
    const float* bias = (const float*)d_in[2];
    float* out        = (float*)d_out;

    if (ws_size < (size_t)W2_BYTES) {
        conv_naive<<<dim3(NW / 256, NCO, NB), 256, 0, stream>>>(x, wgt, bias, out);
        return;
    }

    u16* W2 = (u16*)d_ws;
    wprep<<<(NCO * NCI * NK + 255) / 256, 256, 0, stream>>>(wgt, W2);
    conv_mfma<<<1024, 512, 0, stream>>>(x, W2, bias, out);
}